// Round 15
// baseline (154.380 us; speedup 1.0000x reference)
//
#include <hip/hip_runtime.h>
#include <hip/hip_bf16.h>
#include <stdint.h>

// Problem constants
#define TOKS   262144      // B*S = 32*8192
#define NGRP   16384       // B*G = 32*512
#define EMB    1024
#define HD     64

using bf16x8 = __attribute__((ext_vector_type(8))) short;   // 8 bf16 (4 VGPRs) MFMA operand
using f32x4  = __attribute__((ext_vector_type(4))) float;   // MFMA accumulator

__device__ __forceinline__ unsigned pack2(float a, float b) {
    union { __hip_bfloat162 h; unsigned u; } cvt;
    cvt.h = __float22bfloat162_rn(make_float2(a, b));   // RNE pk-convert
    return cvt.u;
}
__device__ __forceinline__ bf16x8 cvt8(float4 v0, float4 v1) {
    uint4 u;
    u.x = pack2(v0.x, v0.y);
    u.y = pack2(v0.z, v0.w);
    u.z = pack2(v1.x, v1.y);
    u.w = pack2(v1.z, v1.w);
    return __builtin_bit_cast(bf16x8, u);
}
// 3-term row swizzle (r7, measured fewer conflicts than (row&7)<<3):
// 16B-chunk XOR mask within each 128B (64-element) stripe.
__device__ __forceinline__ int swz(int r) {
    return ((r ^ (r >> 2) ^ (r >> 4)) & 7) << 3;
}

// ---------------------------------------------------------------------------
// K0: pack Wo (fp32 [1024][1024]) into MFMA-fragment-linear bf16 (blocks 0..511):
//       packed[((kc*64 + nb)*64 + l)*8 + e] = bf16(Wo[nb*16 + (l&15)][kc*32 + (l>>4)*8 + e])
//     Wq|Wk|Wv (fp32 [64][64]) -> bf16 packed [3][4096] (blocks 512..523).
// ---------------------------------------------------------------------------
__global__ __launch_bounds__(256) void k_cvt(const float* __restrict__ wo,
                                             const float* __restrict__ wq,
                                             const float* __restrict__ wk,
                                             const float* __restrict__ wv,
                                             unsigned short* __restrict__ wob,
                                             unsigned short* __restrict__ wqkvb) {
    int bid = blockIdx.x;
    if (bid < 512) {
        int tid = bid * 256 + threadIdx.x;   // 0..131071, 8 elems each
        int kc  = tid >> 12;                 // k-chunk of 32, 0..31
        int nb  = (tid >> 6) & 63;           // n-block of 16
        int l   = tid & 63;                  // lane within fragment
        int n   = nb * 16 + (l & 15);
        int k   = kc * 32 + (l >> 4) * 8;
        const float* src = wo + (size_t)n * 1024 + k;
        float4 v0 = *(const float4*)(src);
        float4 v1 = *(const float4*)(src + 4);
        *(bf16x8*)(wob + (size_t)tid * 8) = cvt8(v0, v1);
    } else {
        int b = bid - 512;                  // 0..11
        int m = b >> 2;
        const float* src = (m == 0) ? wq : ((m == 1) ? wk : wv);
        int idx = ((b & 3) * 256 + threadIdx.x) * 4;
        float4 v = *(const float4*)(src + idx);
        uint2 p;
        p.x = pack2(v.x, v.y);
        p.y = pack2(v.z, v.w);
        *(uint2*)(wqkvb + m * 4096 + idx) = p;
    }
}

// ---------------------------------------------------------------------------
// K1 (MEGA): fused attention + output GEMM, round-6 structure with
// SWAPPED-OPERAND projections (round 15).
// The proj MFMA C-layout is token-major (lane holds 4 tokens at one d),
// forcing 48 ds_write_b16 + 48 half-extracts per group for the Q/K/PV
// LDS tiles (d-major). For 16x16x32, A and B fragments have IDENTICAL lane
// layouts, so mfma(W, x) instead of mfma(x, W) gives D[m=d][n=token]: each
// lane holds 4 CONSECUTIVE d for ONE token -> every Q/K/PV store becomes a
// single ds_write_b64 (uint2 of the two pack2 dwords, no extracts).
//   - Q (swapped) -> lane's token-row (4c+gbq) of the A-tile, 4x b64
//   - K (swapped) -> kscr row c, 4x b64
//   - V (normal)  -> regs, token-major (PV gather needs this orientation)
//   - energy: unchanged mfma(ka, qb); ka/qb b128 reads, masks = the SAME
//     per-lane values used by the writes (swz(c) / swz(4c+gbq))
//   - PV swapped: o = mfma(V-frag, P-frag). P's k>=16 zero-pad (hi lanes)
//     kills V's j>=16 garbage. V/A2 gathers byte-identical to round 6.
//     Output lane = out[token c][d=nb*16+4q+r] -> 4x b64 overwrite of Q.
// DS ops per group: 76 -> ~40; -48 VALU extracts. Per-element math is
// unchanged (same dot products, same RNE packing, same kc order).
// swz() used on ALL LDS sides incl. phase-2 A-reads (swz(m*16+c)).
// out2-row for token tau = 4*tau + gbq (same bijection as round 6).
// ---------------------------------------------------------------------------
#define SCL 0.0450842200278f   /* log2(e)/32 */

#define MFMA_B16(A, B, Cc) __builtin_amdgcn_mfma_f32_16x16x32_bf16(A, B, Cc, 0, 0, 0)

__global__ __launch_bounds__(512, 2) void k_mega(const float* __restrict__ x,
                                                 const unsigned short* __restrict__ wqkv,
                                                 const unsigned short* __restrict__ wob,
                                                 const float* __restrict__ bias,
                                                 float* __restrict__ C) {
    extern __shared__ __align__(16) unsigned short lds[];
    unsigned short* out2s = lds;               // [64][1024] bf16 A-tile (128 KB)
    unsigned short* kscr  = lds + 65536;       // [8 waves][16][64] K-scratch (16 KB)

    const int t = threadIdx.x;
    const int w = t >> 6, l = t & 63;
    const int c = l & 15, q = l >> 4;
    const int bid   = blockIdx.x;
    const int batch = bid >> 3, q8 = bid & 7;
    unsigned short* kw = kscr + w * 1024;

    const int mK  = swz(c);                    // kscr mask (lane's K row = c)
    const int wq4 = 4 * q;                     // write-col base within 16-block

    // ================= phase 1: attention (8 groups/wave, sequential) =====
    #pragma unroll 1
    for (int i = 0; i < 8; ++i) {
        const int gl   = w * 8 + i;            // local group 0..63
        const int gbq  = gl >> 4;              // local gb 0..3
        const int gcol = gl & 15;              // column stripe
        const size_t tok0 = (size_t)bid * 1024 + (size_t)gl * 16;

        // ---- x frags (fp32 -> bf16 in-register); used as B for Q/K, A for V
        bf16x8 xa[2];
        {
            const float* xp = x + (tok0 + c) * 64 + q * 8;
            #pragma unroll
            for (int kc2 = 0; kc2 < 2; ++kc2) {
                float4 v0 = *(const float4*)(xp + kc2 * 32);
                float4 v1 = *(const float4*)(xp + kc2 * 32 + 4);
                xa[kc2] = cvt8(v0, v1);
            }
        }

        const int row2 = 4 * c + gbq;          // A-tile row of lane's token c
        const int mA   = swz(row2);            // write AND energy-read mask
        unsigned short* qsrow = out2s + (size_t)row2 * 1024 + gcol * 64;

        // ---- Q projection (swapped): lane -> Q[token c][d = nb*16+4q+r] ----
        #pragma unroll
        for (int nb = 0; nb < 4; ++nb) {
            const unsigned short* wp = wqkv + (nb * 16 + c) * 64 + q * 8;
            bf16x8 w0 = *(const bf16x8*)(wp);
            bf16x8 w1 = *(const bf16x8*)(wp + 32);
            f32x4 a2 = (f32x4){0.f, 0.f, 0.f, 0.f};
            a2 = MFMA_B16(w0, xa[0], a2);
            a2 = MFMA_B16(w1, xa[1], a2);
            uint2 u;
            u.x = pack2(a2[0], a2[1]);         // d = 4q+0, 4q+1
            u.y = pack2(a2[2], a2[3]);         // d = 4q+2, 4q+3
            *(uint2*)(qsrow + ((nb * 16 + wq4) ^ mA)) = u;
        }

        // ---- K projection (swapped): lane -> K[token c][d] -> kscr row c ----
        #pragma unroll
        for (int nb = 0; nb < 4; ++nb) {
            const unsigned short* wp = wqkv + 4096 + (nb * 16 + c) * 64 + q * 8;
            bf16x8 w0 = *(const bf16x8*)(wp);
            bf16x8 w1 = *(const bf16x8*)(wp + 32);
            f32x4 a2 = (f32x4){0.f, 0.f, 0.f, 0.f};
            a2 = MFMA_B16(w0, xa[0], a2);
            a2 = MFMA_B16(w1, xa[1], a2);
            uint2 u;
            u.x = pack2(a2[0], a2[1]);
            u.y = pack2(a2[2], a2[3]);
            *(uint2*)(kw + c * 64 + ((nb * 16 + wq4) ^ mK)) = u;
        }

        // ---- V projection (normal, token-major) -> regs ----
        uint2 pkV[4];
        #pragma unroll
        for (int nb = 0; nb < 4; ++nb) {
            const unsigned short* wp = wqkv + 2 * 4096 + (nb * 16 + c) * 64 + q * 8;
            bf16x8 w0 = *(const bf16x8*)(wp);
            bf16x8 w1 = *(const bf16x8*)(wp + 32);
            f32x4 a2 = (f32x4){0.f, 0.f, 0.f, 0.f};
            a2 = MFMA_B16(xa[0], w0, a2);
            a2 = MFMA_B16(xa[1], w1, a2);
            pkV[nb].x = pack2(a2[0], a2[1]);   // tokens 4q+0,1
            pkV[nb].y = pack2(a2[2], a2[3]);   // tokens 4q+2,3
        }

        // ---- energy^T[j][i]: A = K-frag (kscr), B = Q-frag (A-tile) ----
        f32x4 e = (f32x4){0.f, 0.f, 0.f, 0.f};
        #pragma unroll
        for (int kc2 = 0; kc2 < 2; ++kc2) {
            const int L = kc2 * 32 + q * 8;
            bf16x8 ka = *(const bf16x8*)(kw + c * 64 + (L ^ mK));
            bf16x8 qb = *(const bf16x8*)(qsrow + (L ^ mA));
            e = MFMA_B16(ka, qb, e);
        }
        // lane(q,c): e[r] = energy[i=c][j=4q+r]

        // ---- softmax over j (unchanged) ----
        unsigned pa0, pa1;
        {
            float mx = fmaxf(fmaxf(e[0], e[1]), fmaxf(e[2], e[3]));
            mx = fmaxf(mx, __shfl_xor(mx, 16));
            mx = fmaxf(mx, __shfl_xor(mx, 32));
            float p0 = exp2f((e[0] - mx) * SCL);
            float p1 = exp2f((e[1] - mx) * SCL);
            float p2 = exp2f((e[2] - mx) * SCL);
            float p3 = exp2f((e[3] - mx) * SCL);
            float s = p0 + p1 + p2 + p3;
            s += __shfl_xor(s, 16);
            s += __shfl_xor(s, 32);
            float rinv = 1.0f / s;
            pa0 = pack2(p0 * rinv, p1 * rinv);   // j = 4q+0,1
            pa1 = pack2(p2 * rinv, p3 * rinv);   // j = 4q+2,3
        }

        // ---- PV (swapped): o = mfma(V-frag, P-frag); overwrite Q stripe ----
        {
            const int sh0 = (32 * q + c) & 63;
            const int sh1 = (32 * q + 16 + c) & 63;
            const int sv0 = 32 * (q & 1) + c;
            const int sv1 = sv0 + 16;
            const bool hi = (q >= 2);           // k = j >= 16 -> zero pad (in P)
            int a0 = __shfl((int)pa0, sh0);
            int a1 = __shfl((int)pa1, sh0);
            int a2i = __shfl((int)pa0, sh1);
            int a3 = __shfl((int)pa1, sh1);
            uint4 A2u;
            A2u.x = hi ? 0u : (unsigned)a0;
            A2u.y = hi ? 0u : (unsigned)a1;
            A2u.z = hi ? 0u : (unsigned)a2i;
            A2u.w = hi ? 0u : (unsigned)a3;
            bf16x8 A2 = __builtin_bit_cast(bf16x8, A2u);   // P[i=c][j=q*8+e]

            #pragma unroll
            for (int nb = 0; nb < 4; ++nb) {
                uint4 B2u;                      // V[j=q*8+e][d=nb*16+c]
                B2u.x = (unsigned)__shfl((int)pkV[nb].x, sv0);
                B2u.y = (unsigned)__shfl((int)pkV[nb].y, sv0);
                B2u.z = (unsigned)__shfl((int)pkV[nb].x, sv1);
                B2u.w = (unsigned)__shfl((int)pkV[nb].y, sv1);
                bf16x8 B2 = __builtin_bit_cast(bf16x8, B2u);
                f32x4 o = (f32x4){0.f, 0.f, 0.f, 0.f};
                o = MFMA_B16(B2, A2, o);        // out[i=c][d=nb*16+4q+r]
                uint2 u;
                u.x = pack2(o[0], o[1]);
                u.y = pack2(o[2], o[3]);
                *(uint2*)(qsrow + ((nb * 16 + wq4) ^ mA)) = u;
            }
        }
    }

    __syncthreads();   // A-tile complete

    // ================= phase 2: GEMM  C[64][1024] = A @ Wo^T + bias =======
    // wave w: all 64 rows x cols [w*128, w*128+128). No barriers, no staging.
    const unsigned short* gBw = wob + (size_t)(w * 8) * 512 + (size_t)l * 8;
    float bc[8];
    #pragma unroll
    for (int nb = 0; nb < 8; ++nb) bc[nb] = bias[w * 128 + nb * 16 + c];

    f32x4 acc[4][8];
    #pragma unroll
    for (int m = 0; m < 4; ++m)
        #pragma unroll
        for (int nb = 0; nb < 8; ++nb)
            acc[m][nb] = (f32x4){0.f, 0.f, 0.f, 0.f};

    const int mg[4] = {swz(c), swz(16 + c), swz(32 + c), swz(48 + c)};
    bf16x8 bE[8], bO[8], a[4];

    #pragma unroll
    for (int nb = 0; nb < 8; ++nb) bE[nb] = *(const bf16x8*)(gBw + nb * 512);   // kc=0

    #pragma unroll 1
    for (int tt = 0; tt < 16; ++tt) {
        const size_t kb = (size_t)tt * 65536;
        #pragma unroll
        for (int nb = 0; nb < 8; ++nb)          // prefetch odd kc = 2tt+1
            bO[nb] = *(const bf16x8*)(gBw + kb + 32768 + nb * 512);
        {
            const int L = (2 * tt) * 32 + q * 8;
            #pragma unroll
            for (int m = 0; m < 4; ++m)
                a[m] = *(const bf16x8*)(out2s + (size_t)(m * 16 + c) * 1024 + (L ^ mg[m]));
            #pragma unroll
            for (int m = 0; m < 4; ++m)
                #pragma unroll
                for (int nb = 0; nb < 8; ++nb)
                    acc[m][nb] = MFMA_B16(a[m], bE[nb], acc[m][nb]);
        }
        if (tt < 15) {
            #pragma unroll
            for (int nb = 0; nb < 8; ++nb)      // prefetch even kc = 2tt+2
                bE[nb] = *(const bf16x8*)(gBw + kb + 65536 + nb * 512);
        }
        {
            const int L = (2 * tt + 1) * 32 + q * 8;
            #pragma unroll
            for (int m = 0; m < 4; ++m)
                a[m] = *(const bf16x8*)(out2s + (size_t)(m * 16 + c) * 1024 + (L ^ mg[m]));
            #pragma unroll
            for (int m = 0; m < 4; ++m)
                #pragma unroll
                for (int nb = 0; nb < 8; ++nb)
                    acc[m][nb] = MFMA_B16(a[m], bO[nb], acc[m][nb]);
        }
    }

    // ---- epilogue: bias + fp32 store. Global C row for local row lr =
    // m*16 + q*4 + r:  rg = batch*512 + (lr>>2)*32 + q8*4 + (lr&3).
    #pragma unroll
    for (int m = 0; m < 4; ++m) {
        #pragma unroll
        for (int r = 0; r < 4; ++r) {
            const int rg = batch * 512 + (m * 4 + q) * 32 + q8 * 4 + r;
            float* cp = C + (size_t)rg * 1024 + w * 128 + c;
            #pragma unroll
            for (int nb = 0; nb < 8; ++nb)
                cp[nb * 16] = acc[m][nb][r] + bc[nb];
        }
    }
}

// ---------------------------------------------------------------------------
extern "C" void kernel_launch(void* const* d_in, const int* in_sizes, int n_in,
                              void* d_out, int out_size, void* d_ws, size_t ws_size,
                              hipStream_t stream) {
    const float* x  = (const float*)d_in[0];
    const float* wq = (const float*)d_in[1];
    const float* wk = (const float*)d_in[2];
    const float* wv = (const float*)d_in[3];
    const float* wo = (const float*)d_in[4];
    const float* bo = (const float*)d_in[5];
    float* out = (float*)d_out;

    unsigned short* wob   = (unsigned short*)d_ws;           // 1024*1024 bf16 packed (2 MB)
    unsigned short* wqkvb = wob + (size_t)EMB * EMB;         // 3*4096 bf16 (24 KB)

    static int s_once = []() {
        hipFuncSetAttribute((const void*)k_mega,
                            hipFuncAttributeMaxDynamicSharedMemorySize, 147456);
        return 0;
    }();
    (void)s_once;

    k_cvt <<<524, 256, 0, stream>>>(wo, wq, wk, wv, wob, wqkvb);
    k_mega<<<256, 512, 147456, stream>>>(x, wqkvb, wob, bo, out);
}